// Round 14
// baseline (187.596 us; speedup 1.0000x reference)
//
#include <hip/hip_runtime.h>

// x: [T=63, B=1, H=16, S=384, D=128] f32
// y: [T=63, B=1, H=16, D=128, S=384] f32
// out: [63, 1, 16, 384, 384] f32 = broadcast of per-head (mean_t x) @ (mean_t y)
#define T_DIM 63
#define H_DIM 16
#define S_DIM 384
#define D_DIM 128
#define SLICE_ELEMS (H_DIM * S_DIM * D_DIM)        // 786432 floats per t-slice
#define SLICE_F4    (SLICE_ELEMS / 4)              // 196608
#define OUT_TSTRIDE (H_DIM * S_DIM * S_DIM)        // 2359296 floats per t-slice of out
#define W_F4        (OUT_TSTRIDE / 4)              // 589824 float4 per t-slice

typedef float f32x4 __attribute__((ext_vector_type(4)));

// Kernel 1: temporal mean over T for both x and y. Pure read-bound (396 MB).
// nt loads (R7 A/B: nt worth ~15-20% on these streams). Byte-identical to R11.
__global__ __launch_bounds__(256) void treduce_kernel(
    const float* __restrict__ x, const float* __restrict__ y,
    float* __restrict__ xb, float* __restrict__ yb) {
  int tid = blockIdx.x * 256 + threadIdx.x;      // 0 .. 2*SLICE_F4-1
  const f32x4* src;
  f32x4* dst;
  if (tid < SLICE_F4) {
    src = reinterpret_cast<const f32x4*>(x) + tid;
    dst = reinterpret_cast<f32x4*>(xb) + tid;
  } else {
    tid -= SLICE_F4;
    src = reinterpret_cast<const f32x4*>(y) + tid;
    dst = reinterpret_cast<f32x4*>(yb) + tid;
  }
  f32x4 acc = (f32x4)0.f;
#pragma unroll 9
  for (int t = 0; t < T_DIM; ++t) {
    f32x4 v = __builtin_nontemporal_load(src + (size_t)t * SLICE_F4);
    acc += v;
  }
  acc *= (1.0f / (float)T_DIM);
  *dst = acc;
}

// Kernel 2: lean 32x32-tile GEMM writing only the t=0 slice. nt w-store
// (R11 A/B: avoids cross-XCD dirty-line resolution for k3's readers).
// grid (12,12,16) = 2304 blocks, 18 KB LDS. Byte-identical to R11.
__global__ __launch_bounds__(256) void gemm_kernel(
    const float* __restrict__ xb, const float* __restrict__ yb,
    float* __restrict__ out) {
  __shared__ float Bs[128][36];

  const int h  = blockIdx.z;
  const int by = blockIdx.y;
  const int bx = blockIdx.x;
  const int t  = threadIdx.x;

  const float* A = xb + (size_t)h * S_DIM * D_DIM;  // [384][128] row-major
  const float* B = yb + (size_t)h * D_DIM * S_DIM;  // [128][384] row-major

  // Stage B tile: 128 rows x 32 cols = 1024 float4, 4 per thread.
#pragma unroll
  for (int it = 0; it < 4; ++it) {
    int l = t + it * 256;
    int k  = l >> 3;         // 8 float4 per row
    int c4 = l & 7;
    float4 v = *reinterpret_cast<const float4*>(B + (size_t)k * S_DIM + bx * 32 + c4 * 4);
    *reinterpret_cast<float4*>(&Bs[k][c4 * 4]) = v;
  }
  __syncthreads();

  const int row = t >> 3;   // 0..31
  const int c4  = t & 7;    // 0..7

  const f32x4* A4 = reinterpret_cast<const f32x4*>(A + (size_t)(by * 32 + row) * D_DIM);

  f32x4 acc = (f32x4)0.f;
#pragma unroll 8
  for (int k4 = 0; k4 < 32; ++k4) {
    f32x4 a4 = A4[k4];
    f32x4 b0 = *reinterpret_cast<const f32x4*>(&Bs[k4 * 4 + 0][c4 * 4]);
    f32x4 b1 = *reinterpret_cast<const f32x4*>(&Bs[k4 * 4 + 1][c4 * 4]);
    f32x4 b2 = *reinterpret_cast<const f32x4*>(&Bs[k4 * 4 + 2][c4 * 4]);
    f32x4 b3 = *reinterpret_cast<const f32x4*>(&Bs[k4 * 4 + 3][c4 * 4]);
    acc += a4.x * b0;
    acc += a4.y * b1;
    acc += a4.z * b2;
    acc += a4.w * b3;
  }

  // Write ONCE into the t=0 slice — nt store.
  float* o = out + (size_t)h * S_DIM * S_DIM
                 + (size_t)(by * 32 + row) * S_DIM + bx * 32 + c4 * 4;
  __builtin_nontemporal_store(acc, reinterpret_cast<f32x4*>(o));
}

// Kernel 3: pure broadcast, fill geometry (t-major), TWO SLICES PER BLOCK.
// Block (cx, ty) reads its 16KB chunk of the t=0 slice once (L2-hot, same
// XCD: 576 % 8 == 0) and writes it to slices 2*ty+1 and 2*ty+2 from the same
// registers. Halves the L2 read stream (580 -> 290 MB) vs R8/R13 while
// keeping the per-store geometry identical (4 x 1KB contiguous per wave per
// slice). Dependent chain: one load group + two independent store groups.
// grid = (576, 31), block = 256.
__global__ __launch_bounds__(256) void bcast_kernel(float* __restrict__ out) {
  const int i0 = blockIdx.x * 1024 + threadIdx.x;        // chunk base + lane
  const size_t t1 = (size_t)(2 * blockIdx.y + 1) * W_F4;
  const size_t t2 = (size_t)(2 * blockIdx.y + 2) * W_F4;
  const f32x4* src = reinterpret_cast<const f32x4*>(out);
  f32x4* o4 = reinterpret_cast<f32x4*>(out);
  f32x4 v[4];
#pragma unroll
  for (int q = 0; q < 4; ++q) v[q] = src[i0 + q * 256];
#pragma unroll
  for (int q = 0; q < 4; ++q)
    __builtin_nontemporal_store(v[q], o4 + t1 + i0 + q * 256);
#pragma unroll
  for (int q = 0; q < 4; ++q)
    __builtin_nontemporal_store(v[q], o4 + t2 + i0 + q * 256);
}

extern "C" void kernel_launch(void* const* d_in, const int* in_sizes, int n_in,
                              void* d_out, int out_size, void* d_ws, size_t ws_size,
                              hipStream_t stream) {
  const float* x = (const float*)d_in[0];
  const float* y = (const float*)d_in[1];
  float* out = (float*)d_out;

  float* xb = (float*)d_ws;                 // 786432 floats
  float* yb = xb + SLICE_ELEMS;             // 786432 floats (6 MB total)

  treduce_kernel<<<dim3(2 * SLICE_F4 / 256), dim3(256), 0, stream>>>(x, y, xb, yb);
  gemm_kernel<<<dim3(12, 12, H_DIM), dim3(256), 0, stream>>>(xb, yb, out);
  bcast_kernel<<<dim3(W_F4 / 1024, (T_DIM - 1) / 2), dim3(256), 0, stream>>>(out);
}

// Round 15
// 181.205 us; speedup vs baseline: 1.0353x; 1.0353x over previous
//
#include <hip/hip_runtime.h>

// x: [T=63, B=1, H=16, S=384, D=128] f32
// y: [T=63, B=1, H=16, D=128, S=384] f32
// out: [63, 1, 16, 384, 384] f32 = broadcast of per-head (mean_t x) @ (mean_t y)
#define T_DIM 63
#define H_DIM 16
#define S_DIM 384
#define D_DIM 128
#define SLICE_ELEMS (H_DIM * S_DIM * D_DIM)        // 786432 floats per t-slice
#define SLICE_F4    (SLICE_ELEMS / 4)              // 196608
#define OUT_TSTRIDE (H_DIM * S_DIM * S_DIM)        // 2359296 floats per t-slice of out
#define W_F4        (OUT_TSTRIDE / 4)              // 589824 float4 per t-slice

typedef float f32x4 __attribute__((ext_vector_type(4)));

// Kernel 1: temporal mean over T for both x and y. Pure read-bound (396 MB).
// nt loads (R7 A/B: nt worth ~15-20% on these streams).
__global__ __launch_bounds__(256) void treduce_kernel(
    const float* __restrict__ x, const float* __restrict__ y,
    float* __restrict__ xb, float* __restrict__ yb) {
  int tid = blockIdx.x * 256 + threadIdx.x;      // 0 .. 2*SLICE_F4-1
  const f32x4* src;
  f32x4* dst;
  if (tid < SLICE_F4) {
    src = reinterpret_cast<const f32x4*>(x) + tid;
    dst = reinterpret_cast<f32x4*>(xb) + tid;
  } else {
    tid -= SLICE_F4;
    src = reinterpret_cast<const f32x4*>(y) + tid;
    dst = reinterpret_cast<f32x4*>(yb) + tid;
  }
  f32x4 acc = (f32x4)0.f;
#pragma unroll 9
  for (int t = 0; t < T_DIM; ++t) {
    f32x4 v = __builtin_nontemporal_load(src + (size_t)t * SLICE_F4);
    acc += v;
  }
  acc *= (1.0f / (float)T_DIM);
  *dst = acc;
}

// Kernel 2: lean 32x32-tile GEMM writing only the t=0 slice. nt w-store
// (R11 A/B: plain stores leave w dirty in the writer XCD's L2; k3's readers
// on other XCDs then pay cross-XCD dirty-line resolution. nt pushes w to
// L3/HBM at write time -> clean k3 reads. -2.7 us measured).
// grid (12,12,16) = 2304 blocks (9/CU, 36 waves/CU), 18 KB LDS.
__global__ __launch_bounds__(256) void gemm_kernel(
    const float* __restrict__ xb, const float* __restrict__ yb,
    float* __restrict__ out) {
  __shared__ float Bs[128][36];

  const int h  = blockIdx.z;
  const int by = blockIdx.y;
  const int bx = blockIdx.x;
  const int t  = threadIdx.x;

  const float* A = xb + (size_t)h * S_DIM * D_DIM;  // [384][128] row-major
  const float* B = yb + (size_t)h * D_DIM * S_DIM;  // [128][384] row-major

  // Stage B tile: 128 rows x 32 cols = 1024 float4, 4 per thread.
#pragma unroll
  for (int it = 0; it < 4; ++it) {
    int l = t + it * 256;
    int k  = l >> 3;         // 8 float4 per row
    int c4 = l & 7;
    float4 v = *reinterpret_cast<const float4*>(B + (size_t)k * S_DIM + bx * 32 + c4 * 4);
    *reinterpret_cast<float4*>(&Bs[k][c4 * 4]) = v;
  }
  __syncthreads();

  const int row = t >> 3;   // 0..31
  const int c4  = t & 7;    // 0..7

  const f32x4* A4 = reinterpret_cast<const f32x4*>(A + (size_t)(by * 32 + row) * D_DIM);

  f32x4 acc = (f32x4)0.f;
#pragma unroll 8
  for (int k4 = 0; k4 < 32; ++k4) {
    f32x4 a4 = A4[k4];
    f32x4 b0 = *reinterpret_cast<const f32x4*>(&Bs[k4 * 4 + 0][c4 * 4]);
    f32x4 b1 = *reinterpret_cast<const f32x4*>(&Bs[k4 * 4 + 1][c4 * 4]);
    f32x4 b2 = *reinterpret_cast<const f32x4*>(&Bs[k4 * 4 + 2][c4 * 4]);
    f32x4 b3 = *reinterpret_cast<const f32x4*>(&Bs[k4 * 4 + 3][c4 * 4]);
    acc += a4.x * b0;
    acc += a4.y * b1;
    acc += a4.z * b2;
    acc += a4.w * b3;
  }

  // Write ONCE into the t=0 slice — nt store.
  float* o = out + (size_t)h * S_DIM * S_DIM
                 + (size_t)(by * 32 + row) * S_DIM + bx * 32 + c4 * 4;
  __builtin_nontemporal_store(acc, reinterpret_cast<f32x4*>(o));
}

// Kernel 3: pure broadcast, fill geometry (t-major). Block (cx, ty) owns a
// linear 16KB chunk of t-slice ty+1; 4 cached reads of the t=0 slice + 4 nt
// stores, 1KB contiguous per store instr per wave. 576 % 8 == 0 -> all 62
// readers of chunk cx land on one XCD (w reads L2-resident after first touch).
// grid = (576, 62), block = 256. Best of six measured k3 geometries.
__global__ __launch_bounds__(256) void bcast_kernel(float* __restrict__ out) {
  const int i0 = blockIdx.x * 1024 + threadIdx.x;        // chunk base + lane
  const size_t toff = (size_t)(blockIdx.y + 1) * W_F4;   // t = 1..62
  const f32x4* src = reinterpret_cast<const f32x4*>(out);
  f32x4* dst = reinterpret_cast<f32x4*>(out) + toff;
#pragma unroll
  for (int q = 0; q < 4; ++q) {
    int i = i0 + q * 256;
    f32x4 v = src[i];
    __builtin_nontemporal_store(v, dst + i);
  }
}

extern "C" void kernel_launch(void* const* d_in, const int* in_sizes, int n_in,
                              void* d_out, int out_size, void* d_ws, size_t ws_size,
                              hipStream_t stream) {
  const float* x = (const float*)d_in[0];
  const float* y = (const float*)d_in[1];
  float* out = (float*)d_out;

  float* xb = (float*)d_ws;                 // 786432 floats
  float* yb = xb + SLICE_ELEMS;             // 786432 floats (6 MB total)

  treduce_kernel<<<dim3(2 * SLICE_F4 / 256), dim3(256), 0, stream>>>(x, y, xb, yb);
  gemm_kernel<<<dim3(12, 12, H_DIM), dim3(256), 0, stream>>>(xb, yb, out);
  bcast_kernel<<<dim3(W_F4 / 1024, T_DIM - 1), dim3(256), 0, stream>>>(out);
}